// Round 6
// baseline (145.143 us; speedup 1.0000x reference)
//
#include <hip/hip_runtime.h>
#include <hip/hip_cooperative_groups.h>
#include <math.h>
#include <stdint.h>

namespace cg = cooperative_groups;

#define GAMMA 0.7f
#define CAP 96
#define NBLK 256
#define NTHR 512

typedef __attribute__((ext_vector_type(8))) short short8v;   // 8 bf16
typedef __attribute__((ext_vector_type(4))) float f32x4;

__device__ __forceinline__ float sp_dev(float x) {
    return fmaxf(x, 0.0f) + log1pf(expf(-fabsf(x)));
}
__device__ __forceinline__ float gelu_exact(float x) {
    return 0.5f * x * (1.0f + erff(x * 0.70710678118654752f));
}
__device__ __forceinline__ uint16_t f2bf(float x) {
    union { float f; uint32_t u; } c; c.f = x;
    uint32_t u = c.u + 0x7FFFu + ((c.u >> 16) & 1u);
    return (uint16_t)(u >> 16);
}

// 4 lanes per instance; lane g loads row g of the (padded) 4x4 submatrix.
// Tri (K=3): row3=[0,0,0,1] -> traces corrected by -1.
template <int K>
__device__ __forceinline__ void contrib_group(
    const float* __restrict__ A, int n,
    const int* __restrict__ idx, int I, int i, int g, int lane,
    const float (*dc)[8][3], float* __restrict__ cont,
    int* __restrict__ cursor, int* __restrict__ slotbuf) {
    int base = lane & ~3;
    int mynode = (g < K) ? idx[i * K + g] : 0;
    int nb0 = __shfl(mynode, base + 0);
    int nb1 = __shfl(mynode, base + 1);
    int nb2 = __shfl(mynode, base + 2);
    int nb3 = (K == 4) ? __shfl(mynode, base + 3) : 0;

    float r0, r1, r2, r3;
    if (K == 3) {
        if (g < 3) {
            const float* Ar = A + (size_t)mynode * n;
            r0 = Ar[nb0]; r1 = Ar[nb1]; r2 = Ar[nb2]; r3 = 0.0f;
        } else {
            r0 = 0.0f; r1 = 0.0f; r2 = 0.0f; r3 = 1.0f;
        }
    } else {
        const float* Ar = A + (size_t)mynode * n;
        r0 = Ar[nb0]; r1 = Ar[nb1]; r2 = Ar[nb2]; r3 = Ar[nb3];
    }
    float rs = fmaxf(r0 + r1 + r2 + r3, 1e-12f);
    float inv = 1.0f / rs;
    r0 *= inv; r1 *= inv; r2 *= inv; r3 *= inv;

    float M[4][4];
#pragma unroll
    for (int b = 0; b < 4; b++) {
        M[b][0] = __shfl(r0, base + b);
        M[b][1] = __shfl(r1, base + b);
        M[b][2] = __shfl(r2, base + b);
        M[b][3] = __shfl(r3, base + b);
    }

    float t1 = M[0][0] + M[1][1] + M[2][2] + M[3][3];
    float t2 = 0.0f, t3 = 0.0f;
#pragma unroll
    for (int a = 0; a < 4; a++)
#pragma unroll
        for (int b = 0; b < 4; b++) {
            float ab = M[a][b];
            t2 += ab * M[b][a];
#pragma unroll
            for (int c = 0; c < 4; c++) t3 += ab * M[b][c] * M[c][a];
        }
    if (K == 3) { t1 -= 1.0f; t2 -= 1.0f; t3 -= 1.0f; }

#pragma unroll
    for (int L = 0; L < 2; L++) {
        float sims[8], mx = -1e30f;
#pragma unroll
        for (int f = 0; f < 8; f++) {
            sims[f] = dc[L][f][0] * t1 + dc[L][f][1] * t2 + dc[L][f][2] * t3;
            mx = fmaxf(mx, sims[f]);
        }
        float es[8], se = 0.0f;
#pragma unroll
        for (int f = 0; f < 8; f++) { es[f] = expf(sims[f] - mx); se += es[f]; }
        float sinv = 1.0f / se;
        float cn[8];
#pragma unroll
        for (int f = 0; f < 8; f++) cn[f] = es[f] * sinv * sims[f] * (1.0f / (float)K);
        float p0 = (g == 0) ? cn[0] : (g == 1) ? cn[2] : (g == 2) ? cn[4] : cn[6];
        float p1 = (g == 0) ? cn[1] : (g == 1) ? cn[3] : (g == 2) ? cn[5] : cn[7];
        *(float2*)(cont + ((size_t)L * I + i) * 8 + 2 * g) = make_float2(p0, p1);
    }

    if (g < K) {
        int pos = atomicAdd(&cursor[mynode], 1);
        if (pos < CAP) slotbuf[(size_t)mynode * CAP + pos] = i;
    }
}

struct KParams {
    const float* A; const int* tri; const int* cyc;
    const float *Wt0, *Wc0, *g0, *lng0, *lnb0, *w1_0, *b1_0, *w2_0, *b2_0;
    const float *Wt1, *Wc1, *g1, *lng1, *lnb1, *w1_1, *b1_1, *w2_1, *b2_1;
    float* H0; float* tri_c; float* cyc_c;
    int* cursor; int* slotbuf;
    uint16_t *Wb10, *Wb20, *Wb11, *Wb21;
    float* out;
    int n, Itri, Icyc;
};

__global__ __launch_bounds__(NTHR, 2) void uber_kernel(KParams p) {
    cg::grid_group grid = cg::this_grid();
    __shared__ float    dcs[2][2][8][3];   // [m][L][f][p]
    __shared__ uint16_t Xs[16][168];
    __shared__ uint16_t Hs[16][136];
    __shared__ float    Zs[16][129];
    __shared__ float    phi0[16][17];
    __shared__ float    f1[16][16];
    __shared__ float    h0s[16];

    const int tid = threadIdx.x;
    const int bid = blockIdx.x;
    const int nb = gridDim.x;
    const int gtid = bid * NTHR + tid;
    const int gstride = nb * NTHR;
    const int n = p.n;

    // ================= P0a: cursor zero + walk coefs (LDS) + W transposes ====
    for (int i = gtid; i < 2 * n; i += gstride) p.cursor[i] = 0;

    if (tid < 32) {
        int L = tid >> 4, m = (tid >> 3) & 1, f = tid & 7;
        int k = m ? 4 : 3;
        const float* W = L ? (m ? p.Wc1 : p.Wt1) : (m ? p.Wc0 : p.Wt0);
        const float* g = L ? p.g1 : p.g0;
        float S[4][4], Y[4][4];
        for (int a = 0; a < k; a++)
            for (int b = 0; b < k; b++)
                S[a][b] = sp_dev(W[(f * k + a) * k + b]);
        for (int a = 0; a < k; a++)
            for (int b = 0; b < k; b++)
                Y[a][b] = (a == b) ? 0.0f : 0.5f * (S[a][b] + S[b][a]);
        for (int a = 0; a < k; a++) {
            float rs = 0.0f;
            for (int b = 0; b < k; b++) rs += Y[a][b];
            rs = fmaxf(rs, 1e-12f);
            for (int b = 0; b < k; b++) Y[a][b] /= rs;
        }
        float t1 = 0, t2 = 0, t3 = 0;
        for (int a = 0; a < k; a++) t1 += Y[a][a];
        for (int a = 0; a < k; a++)
            for (int b = 0; b < k; b++) t2 += Y[a][b] * Y[b][a];
        for (int a = 0; a < k; a++)
            for (int b = 0; b < k; b++)
                for (int c = 0; c < k; c++) t3 += Y[a][b] * Y[b][c] * Y[c][a];
        dcs[m][L][f][0] = GAMMA * sp_dev(g[0]) * t1;
        dcs[m][L][f][1] = GAMMA * GAMMA * sp_dev(g[1]) * t2;
        dcs[m][L][f][2] = GAMMA * GAMMA * GAMMA * sp_dev(g[2]) * t3;
    }

    for (int idx = gtid; idx < 57344; idx += gstride) {
        if (idx < 4096) {
            int c = idx >> 5, k = idx & 31;
            p.Wb10[idx] = (k < 17) ? f2bf(p.w1_0[k * 128 + c]) : 0;
        } else if (idx < 20480) {
            int e = idx - 4096; int c = e >> 7, k = e & 127;
            p.Wb20[e] = f2bf(p.w2_0[k * 128 + c]);
        } else if (idx < 40960) {
            int e = idx - 20480; int c = e / 160, k = e % 160;
            p.Wb11[e] = (k < 145) ? f2bf(p.w1_1[k * 128 + c]) : 0;
        } else {
            int e = idx - 40960; int c = e >> 7, k = e & 127;
            p.Wb21[e] = f2bf(p.w2_1[k * 128 + c]);
        }
    }

    grid.sync();

    // ================= P0b: contrib (latency) + rowsum (BW), overlapped =====
    {
        int lane = tid & 63, g = tid & 3;
        // tri
        int per = (p.Itri + nb - 1) / nb;
        int lim = bid * per + per;
        if (lim > p.Itri) lim = p.Itri;
        for (int q = bid * per + (tid >> 2); q < lim; q += NTHR / 4)
            contrib_group<3>(p.A, n, p.tri, p.Itri, q, g, lane, dcs[0],
                             p.tri_c, p.cursor, p.slotbuf);
        // cyc
        per = (p.Icyc + nb - 1) / nb;
        lim = bid * per + per;
        if (lim > p.Icyc) lim = p.Icyc;
        for (int q = bid * per + (tid >> 2); q < lim; q += NTHR / 4)
            contrib_group<4>(p.A, n, p.cyc, p.Icyc, q, g, lane, dcs[1],
                             p.cyc_c, p.cursor + n, p.slotbuf + (size_t)n * CAP);
    }
    {
        int wave = tid >> 6, lane = tid & 63;
        int n4 = n >> 2;
        for (int row = bid * 8 + wave; row < n; row += nb * 8) {
            const float4* Ar = (const float4*)(p.A + (size_t)row * n);
            float s = 0.0f;
            for (int i = lane; i < n4; i += 64) {
                float4 v = Ar[i];
                s += v.x + v.y + v.z + v.w;
            }
            for (int off = 32; off > 0; off >>= 1) s += __shfl_down(s, off);
            if (lane == 0) {
                p.H0[row] = s;
                p.out[(size_t)row * 257 + 256] = s;
            }
        }
    }

    grid.sync();

    // ================= P2: row-local tail, one 16-row tile per block ========
    const int ntiles = n / 16;
    for (int t = bid; t < ntiles; t += nb) {
        int v0 = t * 16;
        int wave = tid >> 6;
        int lane = tid & 63;
        int lr = lane & 15, lg = lane >> 4;

        // gather
        {
            int r = tid >> 5;
            int combo = tid & 31;
            int m = combo >> 4, L = (combo >> 3) & 1, f = combo & 7;
            int v = v0 + r;
            int cnt = p.cursor[m * n + v];
            cnt = cnt < CAP ? cnt : CAP;
            const int* bucket = p.slotbuf + ((size_t)(m * n + v)) * CAP;
            const float* c = m ? p.cyc_c : p.tri_c;
            int I = m ? p.Icyc : p.Itri;
            float sum = 0.0f;
            for (int j = 0; j < cnt; j++) {
                int i = bucket[j];
                sum += c[((size_t)L * I + i) * 8 + f];
            }
            if (L == 0) phi0[r][m * 8 + f] = sum;
            else        f1[r][m * 8 + f] = sum;
            if (combo == 0) { float h = p.H0[v]; phi0[r][16] = h; h0s[r] = h; }
        }
        __syncthreads();

        // LN0
        {
            int r = tid >> 5;
            int j = tid & 31;
            float x = (j < 17) ? phi0[r][j] : 0.0f;
            float s1 = x, s2 = x * x;
            for (int o = 16; o > 0; o >>= 1) { s1 += __shfl_xor(s1, o); s2 += __shfl_xor(s2, o); }
            float mu = s1 / 17.0f;
            float rstd = rsqrtf(s2 / 17.0f - mu * mu + 1e-5f);
            Xs[r][j] = (j < 17) ? f2bf((x - mu) * rstd * p.lng0[j] + p.lnb0[j]) : (uint16_t)0;
        }
        __syncthreads();

        // G1 layer0 (K=32)
        {
            int col = wave * 16 + lr;
            f32x4 acc = {0.f, 0.f, 0.f, 0.f};
            short8v a = *(const short8v*)&Xs[lr][lg * 8];
            short8v b = *(const short8v*)(p.Wb10 + (size_t)col * 32 + lg * 8);
            acc = __builtin_amdgcn_mfma_f32_16x16x32_bf16(a, b, acc, 0, 0, 0);
            float bias = p.b1_0[col];
#pragma unroll
            for (int i = 0; i < 4; i++)
                Hs[lg * 4 + i][col] = f2bf(gelu_exact(acc[i] + bias));
        }
        __syncthreads();

        // G2 layer0 -> out cols 128..255 + Zs
        {
            int col = wave * 16 + lr;
            f32x4 acc = {0.f, 0.f, 0.f, 0.f};
#pragma unroll
            for (int ks = 0; ks < 4; ks++) {
                short8v a = *(const short8v*)&Hs[lr][ks * 32 + lg * 8];
                short8v b = *(const short8v*)(p.Wb20 + (size_t)col * 128 + ks * 32 + lg * 8);
                acc = __builtin_amdgcn_mfma_f32_16x16x32_bf16(a, b, acc, 0, 0, 0);
            }
            float bias = p.b2_0[col];
#pragma unroll
            for (int i = 0; i < 4; i++) {
                int row = lg * 4 + i;
                float val = acc[i] + bias;
                p.out[(size_t)(v0 + row) * 257 + 128 + col] = val;
                Zs[row][col] = val;
            }
        }
        __syncthreads();

        // LN1
        {
            int rr = tid >> 5;
            int tt = tid & 31;
            float ph[5];
            float s1 = 0.0f, s2 = 0.0f;
#pragma unroll
            for (int s = 0; s < 5; s++) {
                int j = tt + 32 * s;
                float x = 0.0f;
                if (j < 16) x = f1[rr][j];
                else if (j < 144) x = Zs[rr][j - 16];
                else if (j == 144) x = h0s[rr];
                ph[s] = x;
                if (j < 145) { s1 += x; s2 += x * x; }
            }
            for (int o = 16; o > 0; o >>= 1) { s1 += __shfl_xor(s1, o); s2 += __shfl_xor(s2, o); }
            float mu = s1 / 145.0f;
            float rstd = rsqrtf(s2 / 145.0f - mu * mu + 1e-5f);
#pragma unroll
            for (int s = 0; s < 5; s++) {
                int j = tt + 32 * s;
                Xs[rr][j] = (j < 145) ? f2bf((ph[s] - mu) * rstd * p.lng1[j] + p.lnb1[j]) : (uint16_t)0;
            }
        }
        __syncthreads();

        // G1 layer1 (K=160)
        {
            int col = wave * 16 + lr;
            f32x4 acc = {0.f, 0.f, 0.f, 0.f};
#pragma unroll
            for (int ks = 0; ks < 5; ks++) {
                short8v a = *(const short8v*)&Xs[lr][ks * 32 + lg * 8];
                short8v b = *(const short8v*)(p.Wb11 + (size_t)col * 160 + ks * 32 + lg * 8);
                acc = __builtin_amdgcn_mfma_f32_16x16x32_bf16(a, b, acc, 0, 0, 0);
            }
            float bias = p.b1_1[col];
#pragma unroll
            for (int i = 0; i < 4; i++)
                Hs[lg * 4 + i][col] = f2bf(gelu_exact(acc[i] + bias));
        }
        __syncthreads();

        // G2 layer1 -> out cols 0..127
        {
            int col = wave * 16 + lr;
            f32x4 acc = {0.f, 0.f, 0.f, 0.f};
#pragma unroll
            for (int ks = 0; ks < 4; ks++) {
                short8v a = *(const short8v*)&Hs[lr][ks * 32 + lg * 8];
                short8v b = *(const short8v*)(p.Wb21 + (size_t)col * 128 + ks * 32 + lg * 8);
                acc = __builtin_amdgcn_mfma_f32_16x16x32_bf16(a, b, acc, 0, 0, 0);
            }
            float bias = p.b2_1[col];
#pragma unroll
            for (int i = 0; i < 4; i++) {
                int row = lg * 4 + i;
                p.out[(size_t)(v0 + row) * 257 + col] = acc[i] + bias;
            }
        }
        __syncthreads();
    }
}

extern "C" void kernel_launch(void* const* d_in, const int* in_sizes, int n_in,
                              void* d_out, int out_size, void* d_ws, size_t ws_size,
                              hipStream_t stream) {
    int n    = out_size / 257;          // 4096
    int Itri = in_sizes[1] / 3;         // 30000
    int Icyc = in_sizes[2] / 4;         // 15000

    float* ws = (float*)d_ws;
    KParams hp;
    hp.A    = (const float*)d_in[0];
    hp.tri  = (const int*)d_in[1];
    hp.cyc  = (const int*)d_in[2];
    hp.Wt0  = (const float*)d_in[3];
    hp.Wc0  = (const float*)d_in[4];
    hp.g0   = (const float*)d_in[5];
    hp.lng0 = (const float*)d_in[6];
    hp.lnb0 = (const float*)d_in[7];
    hp.w1_0 = (const float*)d_in[8];
    hp.b1_0 = (const float*)d_in[9];
    hp.w2_0 = (const float*)d_in[10];
    hp.b2_0 = (const float*)d_in[11];
    hp.Wt1  = (const float*)d_in[12];
    hp.Wc1  = (const float*)d_in[13];
    hp.g1   = (const float*)d_in[14];
    hp.lng1 = (const float*)d_in[15];
    hp.lnb1 = (const float*)d_in[16];
    hp.w1_1 = (const float*)d_in[17];
    hp.b1_1 = (const float*)d_in[18];
    hp.w2_1 = (const float*)d_in[19];
    hp.b2_1 = (const float*)d_in[20];

    hp.H0    = ws;                                   // n
    hp.tri_c = ws + n;                               // 2*Itri*8
    hp.cyc_c = hp.tri_c + (size_t)2 * Itri * 8;      // 2*Icyc*8
    hp.cursor  = (int*)(hp.cyc_c + (size_t)2 * Icyc * 8);  // 2n
    hp.slotbuf = hp.cursor + (size_t)2 * n;                // 2n*CAP
    hp.Wb10 = (uint16_t*)(hp.slotbuf + (size_t)2 * n * CAP);
    hp.Wb20 = hp.Wb10 + 128 * 32;
    hp.Wb11 = hp.Wb20 + 128 * 128;
    hp.Wb21 = hp.Wb11 + 128 * 160;
    hp.out  = (float*)d_out;
    hp.n = n; hp.Itri = Itri; hp.Icyc = Icyc;

    void* kargs[] = { (void*)&hp };
    hipLaunchCooperativeKernel((const void*)uber_kernel, dim3(NBLK), dim3(NTHR),
                               kargs, 0, stream);
}

// Round 7
// 90.929 us; speedup vs baseline: 1.5962x; 1.5962x over previous
//
#include <hip/hip_runtime.h>
#include <math.h>
#include <stdint.h>

#define GAMMA 0.7f
#define QCAP 4608
#define NT 1024

typedef __attribute__((ext_vector_type(8))) short short8v;   // 8 bf16
typedef __attribute__((ext_vector_type(4))) float f32x4;

__device__ __forceinline__ float sp_dev(float x) {
    return fmaxf(x, 0.0f) + log1pf(expf(-fabsf(x)));
}
__device__ __forceinline__ float gelu_exact(float x) {
    return 0.5f * x * (1.0f + erff(x * 0.70710678118654752f));
}
__device__ __forceinline__ uint16_t f2bf(float x) {
    union { float f; uint32_t u; } c; c.f = x;
    uint32_t u = c.u + 0x7FFFu + ((c.u >> 16) & 1u);
    return (uint16_t)(u >> 16);
}

// B-fragment for MFMA: bf16x8 of W[k0+j][col], j=0..7, zero beyond kmax.
// W is fp32 row-major [K][128]; strided loads are L2-broadcast across blocks.
__device__ __forceinline__ short8v wfrag(const float* __restrict__ W, int col,
                                         int k0, int kmax) {
    short8v r;
#pragma unroll
    for (int j = 0; j < 8; j++) {
        int k = k0 + j;
        float v = (k < kmax) ? W[(size_t)k * 128 + col] : 0.0f;
        r[j] = (short)f2bf(v);
    }
    return r;
}

__global__ __launch_bounds__(NT) void uber_kernel(
    const float* __restrict__ A, const int* __restrict__ tri, const int* __restrict__ cyc,
    const float* __restrict__ Wt0, const float* __restrict__ Wc0, const float* __restrict__ g0,
    const float* __restrict__ lng0, const float* __restrict__ lnb0,
    const float* __restrict__ w1_0, const float* __restrict__ b1_0,
    const float* __restrict__ w2_0, const float* __restrict__ b2_0,
    const float* __restrict__ Wt1, const float* __restrict__ Wc1, const float* __restrict__ g1,
    const float* __restrict__ lng1, const float* __restrict__ lnb1,
    const float* __restrict__ w1_1, const float* __restrict__ b1_1,
    const float* __restrict__ w2_1, const float* __restrict__ b2_1,
    float* __restrict__ out, int n, int Itri, int Icyc) {

    // queue (scan phase) overlays Xs/Hs/Zs (MFMA tail) -- disjoint lifetimes
    __shared__ __align__(16) char upool[QCAP * 4];           // 18432 B
    int* queue = (int*)upool;
    uint16_t (*Xs)[168] = (uint16_t(*)[168])upool;           // 5376 B
    uint16_t (*Hs)[136] = (uint16_t(*)[136])(upool + 5376);  // 4352 B
    float    (*Zs)[132] = (float(*)[132])(upool + 9728);     // 8448 B
    __shared__ float dcs[2][2][8][3];    // [m][L][f][p]
    __shared__ float phiL0[16][16];
    __shared__ float phiL1[16][16];
    __shared__ float h0s[16];
    __shared__ int qcnt;

    const int tid  = threadIdx.x;
    const int v0   = blockIdx.x * 16;
    const int wave = tid >> 6;
    const int lane = tid & 63;

    // ---------------- init: zero accumulators + walk coefficients ----------
    if (tid < 256) { ((float*)phiL0)[tid] = 0.0f; ((float*)phiL1)[tid] = 0.0f; }
    if (tid == 0) qcnt = 0;
    if (tid < 32) {
        int L = tid >> 4, m = (tid >> 3) & 1, f = tid & 7;
        int k = m ? 4 : 3;
        const float* W = L ? (m ? Wc1 : Wt1) : (m ? Wc0 : Wt0);
        const float* g = L ? g1 : g0;
        float S[4][4], Y[4][4];
        for (int a = 0; a < k; a++)
            for (int b = 0; b < k; b++)
                S[a][b] = sp_dev(W[(f * k + a) * k + b]);
        for (int a = 0; a < k; a++)
            for (int b = 0; b < k; b++)
                Y[a][b] = (a == b) ? 0.0f : 0.5f * (S[a][b] + S[b][a]);
        for (int a = 0; a < k; a++) {
            float rs = 0.0f;
            for (int b = 0; b < k; b++) rs += Y[a][b];
            rs = fmaxf(rs, 1e-12f);
            for (int b = 0; b < k; b++) Y[a][b] /= rs;
        }
        float t1 = 0, t2 = 0, t3 = 0;
        for (int a = 0; a < k; a++) t1 += Y[a][a];
        for (int a = 0; a < k; a++)
            for (int b = 0; b < k; b++) t2 += Y[a][b] * Y[b][a];
        for (int a = 0; a < k; a++)
            for (int b = 0; b < k; b++)
                for (int c = 0; c < k; c++) t3 += Y[a][b] * Y[b][c] * Y[c][a];
        dcs[m][L][f][0] = GAMMA * sp_dev(g[0]) * t1;
        dcs[m][L][f][1] = GAMMA * GAMMA * sp_dev(g[1]) * t2;
        dcs[m][L][f][2] = GAMMA * GAMMA * GAMMA * sp_dev(g[2]) * t3;
    }

    // ---------------- rowsum: wave w streams row v0+w (coalesced) ----------
    {
        int rr = wave;                       // 0..15
        const float4* Ar = (const float4*)(A + (size_t)(v0 + rr) * n);
        int n4 = n >> 2;                     // 1024
        float s0 = 0, s1 = 0, s2 = 0, s3 = 0;
        for (int i = lane; i < n4; i += 256) {
            float4 a = Ar[i], b = Ar[i + 64], c = Ar[i + 128], d = Ar[i + 192];
            s0 += a.x + a.y + a.z + a.w;
            s1 += b.x + b.y + b.z + b.w;
            s2 += c.x + c.y + c.z + c.w;
            s3 += d.x + d.y + d.z + d.w;
        }
        float s = (s0 + s1) + (s2 + s3);
        for (int o = 32; o > 0; o >>= 1) s += __shfl_down(s, o);
        if (lane == 0) {
            h0s[rr] = s;
            out[(size_t)(v0 + rr) * 257 + 256] = s;
        }
    }
    __syncthreads();

    // ---------------- scan: membership test of all instances ---------------
    {
        int tot = Itri + Icyc;
        for (int base = 0; base < tot; base += NT) {
            int inst = base + tid;
            if (inst >= tot) break;
            int hit = 0;
            if (inst < Itri) {
                const int* p = tri + inst * 3;
#pragma unroll
                for (int j = 0; j < 3; j++) hit |= ((unsigned)(p[j] - v0) < 16u);
            } else {
                const int* p = cyc + (size_t)(inst - Itri) * 4;
#pragma unroll
                for (int j = 0; j < 4; j++) hit |= ((unsigned)(p[j] - v0) < 16u);
            }
            if (hit) {
                int q = atomicAdd(&qcnt, 1);
                if (q < QCAP) queue[q] = inst;
            }
        }
    }
    __syncthreads();

    // ---------------- drain: per-instance traces + softmax -> LDS phi ------
    {
        int qn = qcnt < QCAP ? qcnt : QCAP;
        for (int qi = tid; qi < qn; qi += NT) {
            int inst = queue[qi];
            bool isTri = inst < Itri;
            int m = isTri ? 0 : 1;
            float kinv = isTri ? (1.0f / 3.0f) : 0.25f;
            int nd[4];
            if (isTri) {
                const int* p = tri + inst * 3;
                nd[0] = p[0]; nd[1] = p[1]; nd[2] = p[2]; nd[3] = 0;
            } else {
                const int* p = cyc + (size_t)(inst - Itri) * 4;
                nd[0] = p[0]; nd[1] = p[1]; nd[2] = p[2]; nd[3] = p[3];
            }
            // padded 4x4 transition matrix (tri: row3=[0,0,0,1], traces -1)
            float M[4][4];
#pragma unroll
            for (int a = 0; a < 4; a++) {
                float rs = 0.0f;
#pragma unroll
                for (int b = 0; b < 4; b++) {
                    float v;
                    if (isTri)
                        v = (a < 3 && b < 3) ? A[(size_t)nd[a] * n + nd[b]]
                                             : ((a == 3 && b == 3) ? 1.0f : 0.0f);
                    else
                        v = A[(size_t)nd[a] * n + nd[b]];
                    M[a][b] = v; rs += v;
                }
                rs = fmaxf(rs, 1e-12f);
                float inv = 1.0f / rs;
#pragma unroll
                for (int b = 0; b < 4; b++) M[a][b] *= inv;
            }
            float t1 = M[0][0] + M[1][1] + M[2][2] + M[3][3];
            float t2 = 0, t3 = 0;
#pragma unroll
            for (int a = 0; a < 4; a++)
#pragma unroll
                for (int b = 0; b < 4; b++) {
                    float ab = M[a][b];
                    t2 += ab * M[b][a];
                    float a3 = 0;
#pragma unroll
                    for (int c = 0; c < 4; c++) a3 += M[b][c] * M[c][a];
                    t3 += ab * a3;
                }
            if (isTri) { t1 -= 1.0f; t2 -= 1.0f; t3 -= 1.0f; }

            float cn[2][8];
#pragma unroll
            for (int L = 0; L < 2; L++) {
                float sims[8], mx = -1e30f;
#pragma unroll
                for (int f = 0; f < 8; f++) {
                    sims[f] = dcs[m][L][f][0] * t1 + dcs[m][L][f][1] * t2 +
                              dcs[m][L][f][2] * t3;
                    mx = fmaxf(mx, sims[f]);
                }
                float se = 0;
#pragma unroll
                for (int f = 0; f < 8; f++) { float e = expf(sims[f] - mx); cn[L][f] = e; se += e; }
                float si = 1.0f / se;
#pragma unroll
                for (int f = 0; f < 8; f++) cn[L][f] = cn[L][f] * si * sims[f] * kinv;
            }
            int K = isTri ? 3 : 4;
#pragma unroll
            for (int j = 0; j < 4; j++) {
                if (j >= K) break;
                int r = nd[j] - v0;
                if ((unsigned)r < 16u) {
#pragma unroll
                    for (int f = 0; f < 8; f++) {
                        atomicAdd(&phiL0[r][m * 8 + f], cn[0][f]);
                        atomicAdd(&phiL1[r][m * 8 + f], cn[1][f]);
                    }
                }
            }
        }
    }
    __syncthreads();

    // ---------------- LN0 -> Xs[:,0..31] -----------------------------------
    if (tid < 512) {
        int r = tid >> 5;
        int j = tid & 31;
        float x = (j < 16) ? phiL0[r][j] : (j == 16 ? h0s[r] : 0.0f);
        float s1 = x, s2 = x * x;
        for (int o = 16; o > 0; o >>= 1) { s1 += __shfl_xor(s1, o); s2 += __shfl_xor(s2, o); }
        float mu = s1 / 17.0f;
        float rstd = rsqrtf(s2 / 17.0f - mu * mu + 1e-5f);
        Xs[r][j] = (j < 17) ? f2bf((x - mu) * rstd * lng0[j] + lnb0[j]) : (uint16_t)0;
    }
    __syncthreads();

    // ---------------- G1 layer0 (K=32) -------------------------------------
    if (tid < 512) {
        int w8 = tid >> 6, lr = lane & 15, lg = lane >> 4;
        int col = w8 * 16 + lr;
        f32x4 acc = {0.f, 0.f, 0.f, 0.f};
        short8v a = *(const short8v*)&Xs[lr][lg * 8];
        short8v b = wfrag(w1_0, col, lg * 8, 17);
        acc = __builtin_amdgcn_mfma_f32_16x16x32_bf16(a, b, acc, 0, 0, 0);
        float bias = b1_0[col];
#pragma unroll
        for (int i = 0; i < 4; i++)
            Hs[lg * 4 + i][col] = f2bf(gelu_exact(acc[i] + bias));
    }
    __syncthreads();

    // ---------------- G2 layer0 -> out[:,128..255] + Zs --------------------
    if (tid < 512) {
        int w8 = tid >> 6, lr = lane & 15, lg = lane >> 4;
        int col = w8 * 16 + lr;
        f32x4 acc = {0.f, 0.f, 0.f, 0.f};
#pragma unroll
        for (int ks = 0; ks < 4; ks++) {
            short8v a = *(const short8v*)&Hs[lr][ks * 32 + lg * 8];
            short8v b = wfrag(w2_0, col, ks * 32 + lg * 8, 128);
            acc = __builtin_amdgcn_mfma_f32_16x16x32_bf16(a, b, acc, 0, 0, 0);
        }
        float bias = b2_0[col];
#pragma unroll
        for (int i = 0; i < 4; i++) {
            int row = lg * 4 + i;
            float val = acc[i] + bias;
            out[(size_t)(v0 + row) * 257 + 128 + col] = val;
            Zs[row][col] = val;
        }
    }
    __syncthreads();

    // ---------------- LN1 -> Xs[:,0..159] ----------------------------------
    if (tid < 512) {
        int rr = tid >> 5;
        int t = tid & 31;
        float ph[5];
        float s1 = 0.0f, s2 = 0.0f;
#pragma unroll
        for (int s = 0; s < 5; s++) {
            int j = t + 32 * s;
            float x = 0.0f;
            if (j < 16) x = phiL1[rr][j];
            else if (j < 144) x = Zs[rr][j - 16];
            else if (j == 144) x = h0s[rr];
            ph[s] = x;
            if (j < 145) { s1 += x; s2 += x * x; }
        }
        for (int o = 16; o > 0; o >>= 1) { s1 += __shfl_xor(s1, o); s2 += __shfl_xor(s2, o); }
        float mu = s1 / 145.0f;
        float rstd = rsqrtf(s2 / 145.0f - mu * mu + 1e-5f);
#pragma unroll
        for (int s = 0; s < 5; s++) {
            int j = t + 32 * s;
            Xs[rr][j] = (j < 145) ? f2bf((ph[s] - mu) * rstd * lng1[j] + lnb1[j])
                                  : (uint16_t)0;
        }
    }
    __syncthreads();

    // ---------------- G1 layer1 (K=160) ------------------------------------
    if (tid < 512) {
        int w8 = tid >> 6, lr = lane & 15, lg = lane >> 4;
        int col = w8 * 16 + lr;
        f32x4 acc = {0.f, 0.f, 0.f, 0.f};
#pragma unroll
        for (int ks = 0; ks < 5; ks++) {
            short8v a = *(const short8v*)&Xs[lr][ks * 32 + lg * 8];
            short8v b = wfrag(w1_1, col, ks * 32 + lg * 8, 145);
            acc = __builtin_amdgcn_mfma_f32_16x16x32_bf16(a, b, acc, 0, 0, 0);
        }
        float bias = b1_1[col];
#pragma unroll
        for (int i = 0; i < 4; i++)
            Hs[lg * 4 + i][col] = f2bf(gelu_exact(acc[i] + bias));
    }
    __syncthreads();

    // ---------------- G2 layer1 -> out[:,0..127] ---------------------------
    if (tid < 512) {
        int w8 = tid >> 6, lr = lane & 15, lg = lane >> 4;
        int col = w8 * 16 + lr;
        f32x4 acc = {0.f, 0.f, 0.f, 0.f};
#pragma unroll
        for (int ks = 0; ks < 4; ks++) {
            short8v a = *(const short8v*)&Hs[lr][ks * 32 + lg * 8];
            short8v b = wfrag(w2_1, col, ks * 32 + lg * 8, 128);
            acc = __builtin_amdgcn_mfma_f32_16x16x32_bf16(a, b, acc, 0, 0, 0);
        }
        float bias = b2_1[col];
#pragma unroll
        for (int i = 0; i < 4; i++) {
            int row = lg * 4 + i;
            out[(size_t)(v0 + row) * 257 + col] = acc[i] + bias;
        }
    }
}

extern "C" void kernel_launch(void* const* d_in, const int* in_sizes, int n_in,
                              void* d_out, int out_size, void* d_ws, size_t ws_size,
                              hipStream_t stream) {
    const float* A    = (const float*)d_in[0];
    const int*   tri  = (const int*)d_in[1];
    const int*   cyc  = (const int*)d_in[2];

    int n    = out_size / 257;          // 4096
    int Itri = in_sizes[1] / 3;         // 30000
    int Icyc = in_sizes[2] / 4;         // 15000

    uber_kernel<<<n / 16, NT, 0, stream>>>(
        A, tri, cyc,
        (const float*)d_in[3], (const float*)d_in[4], (const float*)d_in[5],
        (const float*)d_in[6], (const float*)d_in[7],
        (const float*)d_in[8], (const float*)d_in[9],
        (const float*)d_in[10], (const float*)d_in[11],
        (const float*)d_in[12], (const float*)d_in[13], (const float*)d_in[14],
        (const float*)d_in[15], (const float*)d_in[16],
        (const float*)d_in[17], (const float*)d_in[18],
        (const float*)d_in[19], (const float*)d_in[20],
        (float*)d_out, n, Itri, Icyc);
}